// Round 8
// baseline (290.769 us; speedup 1.0000x reference)
//
#include <hip/hip_runtime.h>
#include <math.h>

#define BS   2048
#define SEQ  50
#define NPOS (BS * SEQ)

typedef __attribute__((ext_vector_type(8))) short bf16x8;   // 8 bf16 = 4 VGPR
typedef __attribute__((ext_vector_type(4))) float f32x4;

__device__ __forceinline__ float sigf(float x) { return 1.0f / (1.0f + __expf(-x)); }
__device__ __forceinline__ float tanhfast(float x) {
    float e = __expf(2.0f * x);
    return 1.0f - 2.0f / (e + 1.0f);
}
__device__ __forceinline__ unsigned short bfrn(float x) {   // fp32 -> bf16 rne
    unsigned int u = __float_as_uint(x);
    u += 0x7FFFu + ((u >> 16) & 1u);
    return (unsigned short)(u >> 16);
}
__device__ __forceinline__ float bf2f(unsigned short h) {
    return __uint_as_float(((unsigned int)h) << 16);
}

#define FMA4(A, X, W) \
    A = fmaf((X).x, (W).x, A); A = fmaf((X).y, (W).y, A); \
    A = fmaf((X).z, (W).z, A); A = fmaf((X).w, (W).w, A);

// ---------------------------------------------------------------------------
// Precomputed attention tables (position-independent):
//   Wvf[64][10]: Wv . Wf(:,0:10)
//   Ce [64][9]:  (Wf(:,10+e)+bf) . Wv
//   Ag [4][10][7]: g_h[k] = Ag[h][k][0:6].self6 + Ag[h][k][6]
//   Bd [9][4][7]:  dd[e][h] = Bd[e][h][0:6].self6 + Bd[e][h][6]
// ---------------------------------------------------------------------------
__device__ float Wvf_d[640];
__device__ float Ce_d[576];
__device__ float Ag_d[280];
__device__ float Bd_d[252];

// ---------------------------------------------------------------------------
// prep: blocks 0..47 MFMA weight fragments; blocks 48..50 Wvf/Ce (64-FMA,
// thread-parallel); block 51 Ag/Bd TWO-STAGE: G,D into LDS (64-FMA each),
// sync, then 16-FMA folds.  (R5-R7's flat Ag/Bd build was 1024 serial FMA +
// 2048 scalar loads per element — a ~40us latency chain. This removes it.)
// ---------------------------------------------------------------------------
__global__ __launch_bounds__(512) void prep_all(
    const float* __restrict__ Wih, const float* __restrict__ Whh,
    bf16x8* __restrict__ whF, bf16x8* __restrict__ wiF,
    const float* __restrict__ Wf, const float* __restrict__ bf,
    const float* __restrict__ Wq, const float* __restrict__ bq,
    const float* __restrict__ Wv,
    const float* __restrict__ Wk, const float* __restrict__ bk)
{
    __shared__ float sG[640];   // G[n][k] = Wq[n,:].Wf[:,k]
    __shared__ float sD[576];   // D[e][n]

    if (blockIdx.x < 48) {
        int id = blockIdx.x * 512 + threadIdx.x;
        const float* src;
        bf16x8* dst;
        int p;
        if (id < 16384) {
            int l = id & 63, frag = id >> 6;        // 0..255
            p = frag & 1;
            int kc = (frag >> 1) & 3, ti = (frag >> 3) & 3, w = frag >> 5;
            int n  = (w + 8 * ti) * 16 + (l & 15);
            int k0 = kc * 32 + (l >> 4) * 8;
            src = &Whh[n * 128 + k0];
            dst = &whF[frag * 64 + l];
        } else {
            int id2 = id - 16384;
            int l = id2 & 63, frag = id2 >> 6;      // 0..127
            p = frag & 1;
            int kc = (frag >> 1) & 1, tile = frag >> 2;
            int n  = tile * 16 + (l & 15);
            int k0 = kc * 32 + (l >> 4) * 8;
            src = &Wih[n * 64 + k0];
            dst = &wiF[frag * 64 + l];
        }
        bf16x8 v;
        #pragma unroll
        for (int j = 0; j < 8; ++j) {
            float x = src[j];
            unsigned short hi = bfrn(x);
            unsigned short r  = p ? bfrn(x - bf2f(hi)) : hi;
            v[j] = (short)r;
        }
        *dst = v;
        return;
    }

    if (blockIdx.x < 51) {               // Wvf (640) + Ce (576), flat
        int i = (blockIdx.x - 48) * 512 + threadIdx.x;   // 0..1535
        if (i >= 1216) return;
        if (i < 640) {
            int o = i / 10, k = i % 10;
            float s = 0.f;
            #pragma unroll 8
            for (int j = 0; j < 64; ++j) s = fmaf(Wv[o * 64 + j], Wf[j * 19 + k], s);
            Wvf_d[i] = s;
        } else {
            int i2 = i - 640;
            int o = i2 / 9, e = i2 % 9;
            float s = 0.f;
            #pragma unroll 8
            for (int j = 0; j < 64; ++j)
                s = fmaf(Wf[j * 19 + 10 + e] + bf[j], Wv[o * 64 + j], s);
            Ce_d[i2] = s;
        }
        return;
    }

    // block 51: stage 1 — G and D into LDS
    const int t = threadIdx.x;
    for (int i = t; i < 1216; i += 512) {
        if (i < 640) {
            int n = i / 10, k = i % 10;
            float s = 0.f;
            #pragma unroll 8
            for (int j = 0; j < 64; ++j) s = fmaf(Wq[n * 64 + j], Wf[j * 19 + k], s);
            sG[i] = s;
        } else {
            int i2 = i - 640;
            int e = i2 >> 6, n = i2 & 63;
            float s = bq[n];
            #pragma unroll 8
            for (int j = 0; j < 64; ++j)
                s = fmaf(Wf[j * 19 + 10 + e] + bf[j], Wq[n * 64 + j], s);
            sD[i2] = s;
        }
    }
    __syncthreads();
    // stage 2 — fold with Wk/bk (16 FMA each)
    for (int i = t; i < 532; i += 512) {
        if (i < 280) {                   // Ag: i = (h*10+k)*7 + jj
            int h = i / 70, rem = i % 70, k = rem / 7, jj = rem % 7;
            float s = 0.f;
            #pragma unroll
            for (int d = 0; d < 16; ++d) {
                int n = h * 16 + d;
                float wkj = (jj < 6) ? Wk[n * 6 + jj] : bk[n];
                s = fmaf(wkj, sG[n * 10 + k], s);
            }
            Ag_d[i] = s;
        } else {                         // Bd: i4 = (e*4+h)*7 + jj
            int i4 = i - 280;
            int e = i4 / 28, rem = i4 % 28, h = rem / 7, jj = rem % 7;
            float s = 0.f;
            #pragma unroll
            for (int d = 0; d < 16; ++d) {
                int n = h * 16 + d;
                float wkj = (jj < 6) ? Wk[n * 6 + jj] : bk[n];
                s = fmaf(wkj, sD[e * 64 + n], s);
            }
            Bd_d[i4] = s;
        }
    }
}

// ---------------------------------------------------------------------------
// Kernel A v5: barrier-free, LDS-free shuffle attention.
// Lane map: o = h*16 + j  (h = head, j = slot).
//   j<10: g[h][j]  (affine in self6)          j<9: att/exp for edge j
//   rbar[h][j] for k=j<10                      all: ctx[o]
// All cross-lane data moves are same-wave shuffles:
//   self6 / raw10 / mask: bpermute from staged-in-register seq/et/mask
//   g, exp, rbar: width-16 shuffles (head-local)
//   softmax: width-16 butterfly with -3e38 padding (j>=9)
// ZERO __syncthreads, ZERO LDS -> no phase-drain chain; prefetch spans body.
// ---------------------------------------------------------------------------
__global__ __launch_bounds__(64, 4) void edge_attn_ctx(
    const float* __restrict__ seqs,   // [BS,SEQ,3,3,6]
    const float* __restrict__ ets,    // [BS,SEQ,3,3,4]
    const int*   __restrict__ masks,  // [BS,SEQ,3,3]
    const float* __restrict__ bv,
    float* __restrict__ ctx)          // [BS,SEQ,64]
{
    const int o = threadIdx.x;
    const int j = o & 15, h = o >> 4;
    const int j6 = j * 6, j4 = j * 4;

    // per-lane tables (clamped indices for pad lanes; their results unused)
    const int jA = (j < 10) ? j : 9;
    const int jB = (j < 9)  ? j : 8;
    float Agr[7], Bdr[7];
    #pragma unroll
    for (int q = 0; q < 7; ++q) Agr[q] = Ag_d[(h * 10 + jA) * 7 + q];
    #pragma unroll
    for (int q = 0; q < 7; ++q) Bdr[q] = Bd_d[(jB * 4 + h) * 7 + q];
    float Wvfr[10];
    #pragma unroll
    for (int k = 0; k < 10; ++k) Wvfr[k] = Wvf_d[o * 10 + k];
    const float bvr = bv[o];
    float Cer[9];
    #pragma unroll
    for (int e = 0; e < 9; ++e) Cer[e] = Ce_d[o * 9 + e] + bvr;

    // rbar gather indices (loop-invariant): x[e][j] lives in
    //   seq lane e*6+j (j<6)  or  et lane e*4+(j-6) (6<=j<10)
    const bool selR = (j < 6);
    const int jc = selR ? j : 0;
    const int jm = (j >= 6) ? (j - 6) : 0;

    // prefetch first position
    float r_seq = 0.f, r_et = 0.f; int r_mask = 0;
    if (o < 54) r_seq  = seqs[blockIdx.x * 54 + o];
    if (o < 36) r_et   = ets[blockIdx.x * 36 + o];
    if (o < 9)  r_mask = masks[blockIdx.x * 9 + o];

    for (int p = blockIdx.x; p < NPOS; p += gridDim.x) {
        const float cs = r_seq, cet = r_et; const int cm = r_mask;

        // issue next-position prefetch (consumed next iteration)
        {
            int pn = p + gridDim.x;
            if (pn < NPOS) {
                if (o < 54) r_seq  = seqs[pn * 54 + o];
                if (o < 36) r_et   = ets[pn * 36 + o];
                if (o < 9)  r_mask = masks[pn * 9 + o];
            }
        }

        // ---- self6 broadcast (lanes 24..29 of staged seq) ----
        float c0 = __shfl(cs, 24), c1 = __shfl(cs, 25), c2 = __shfl(cs, 26),
              c3 = __shfl(cs, 27), c4 = __shfl(cs, 28), c5 = __shfl(cs, 29);

        // ---- g[h][j] (j<10) and dd[j][h] (j<9), affine in self6 ----
        float g = Agr[6];
        g = fmaf(c0, Agr[0], g); g = fmaf(c1, Agr[1], g);
        g = fmaf(c2, Agr[2], g); g = fmaf(c3, Agr[3], g);
        g = fmaf(c4, Agr[4], g); g = fmaf(c5, Agr[5], g);
        float tt = Bdr[6];
        tt = fmaf(c0, Bdr[0], tt); tt = fmaf(c1, Bdr[1], tt);
        tt = fmaf(c2, Bdr[2], tt); tt = fmaf(c3, Bdr[3], tt);
        tt = fmaf(c4, Bdr[4], tt); tt = fmaf(c5, Bdr[5], tt);

        // ---- att[j][h] = 0.25*(raw10_j . g_h + dd), mask, pad ----
        float a = tt;
        #pragma unroll
        for (int k = 0; k < 6; ++k)
            a = fmaf(__shfl(cs, j6 + k), __shfl(g, k, 16), a);
        #pragma unroll
        for (int k = 6; k < 10; ++k)
            a = fmaf(__shfl(cet, j4 + (k - 6)), __shfl(g, k, 16), a);
        a *= 0.25f;
        int mk = __shfl(cm, j);
        a = (mk == 0) ? -1.0e10f : a;
        if (j >= 9) a = -3.0e38f;                 // pad lanes lose max, exp->0

        // ---- softmax over 9 edges: width-16 butterflies ----
        float mx = a;
        mx = fmaxf(mx, __shfl_xor(mx, 1, 16));
        mx = fmaxf(mx, __shfl_xor(mx, 2, 16));
        mx = fmaxf(mx, __shfl_xor(mx, 4, 16));
        mx = fmaxf(mx, __shfl_xor(mx, 8, 16));
        float ex = __expf(a - mx);
        float ss = ex;
        ss += __shfl_xor(ss, 1, 16);
        ss += __shfl_xor(ss, 2, 16);
        ss += __shfl_xor(ss, 4, 16);
        ss += __shfl_xor(ss, 8, 16);

        // ---- broadcast the 9 edge weights to all lanes of the head ----
        float exe[9];
        #pragma unroll
        for (int e = 0; e < 9; ++e) exe[e] = __shfl(ex, e, 16);

        // ---- rbar[h][j] = sum_e exe[e]*raw10[e][j]  (j<10 meaningful) ----
        float rb = 0.f;
        #pragma unroll
        for (int e = 0; e < 9; ++e) {
            float xa = __shfl(cs,  e * 6 + jc);
            float xb = __shfl(cet, e * 4 + jm);
            rb = fmaf(exe[e], selR ? xa : xb, rb);
        }

        // ---- ctx[o] = (rbar_h . Wvf[o] + sum_e p Ce'[o][e]) / ssum ----
        float acc = 0.f;
        #pragma unroll
        for (int k = 0; k < 10; ++k)
            acc = fmaf(__shfl(rb, k, 16), Wvfr[k], acc);
        #pragma unroll
        for (int e = 0; e < 9; ++e)
            acc = fmaf(exe[e], Cer[e], acc);
        ctx[p * 64 + o] = acc * (1.0f / ss);
    }
}

// ---------------------------------------------------------------------------
// Kernel C v12: pair-step MFMA LSTM (unchanged; 115-123 us).
// ---------------------------------------------------------------------------
#define MFMA16(A, B, C) __builtin_amdgcn_mfma_f32_16x16x32_bf16(A, B, C, 0, 0, 0)
#define MM4(F, W0, W1, W2, W3) \
    a0 = MFMA16(F, W0, a0); a1 = MFMA16(F, W1, a1); \
    a2 = MFMA16(F, W2, a2); a3 = MFMA16(F, W3, a3);

#define HPASS \
    MM4(hfh[0], whr[0][0][0], whr[1][0][0], whr[2][0][0], whr[3][0][0]) \
    MM4(hfh[1], whr[0][1][0], whr[1][1][0], whr[2][1][0], whr[3][1][0]) \
    MM4(hfh[2], whr[0][2][0], whr[1][2][0], whr[2][2][0], whr[3][2][0]) \
    MM4(hfh[3], whr[0][3][0], whr[1][3][0], whr[2][3][0], whr[3][3][0]) \
    MM4(hfl[0], whr[0][0][0], whr[1][0][0], whr[2][0][0], whr[3][0][0]) \
    MM4(hfl[1], whr[0][1][0], whr[1][1][0], whr[2][1][0], whr[3][1][0]) \
    MM4(hfl[2], whr[0][2][0], whr[1][2][0], whr[2][2][0], whr[3][2][0]) \
    MM4(hfl[3], whr[0][3][0], whr[1][3][0], whr[2][3][0], whr[3][3][0]) \
    MM4(hfh[0], whr[0][0][1], whr[1][0][1], whr[2][0][1], whr[3][0][1]) \
    MM4(hfh[1], whr[0][1][1], whr[1][1][1], whr[2][1][1], whr[3][1][1]) \
    MM4(hfh[2], whr[0][2][1], whr[1][2][1], whr[2][2][1], whr[3][2][1]) \
    MM4(hfh[3], whr[0][3][1], whr[1][3][1], whr[2][3][1], whr[3][3][1])

#define REDIST_E(ch, g0, g1) { \
    float s2_ = __shfl_xor(ch[2], 32), s3_ = __shfl_xor(ch[3], 32); \
    g0 = lolq ? ch[0] : s2_;  g1 = lolq ? ch[1] : s3_; }
#define REDIST_O(ch, g0, g1) { \
    float s0_ = __shfl_xor(ch[0], 32), s1_ = __shfl_xor(ch[1], 32); \
    g0 = lolq ? s0_ : ch[2];  g1 = lolq ? s1_ : ch[3]; }

#define PWBODY(gi0,gf0,gg0,go0,gi1,gf1,gg1,go1, WB0, WB1) { \
    float i0_ = sigf(gi0 + bi), f0_ = sigf(gf0 + bff); \
    float gA_ = tanhfast(gg0 + bg), o0_ = sigf(go0 + bo); \
    c20 = fmaf(f0_, c20, i0_ * gA_); \
    float hv0_ = o0_ * tanhfast(c20); \
    float i1_ = sigf(gi1 + bi), f1_ = sigf(gf1 + bff); \
    float gB_ = tanhfast(gg1 + bg), o1_ = sigf(go1 + bo); \
    c21 = fmaf(f1_, c21, i1_ * gB_); \
    float hv1_ = o1_ * tanhfast(c21); \
    unsigned short hh0_ = bfrn(hv0_), hh1_ = bfrn(hv1_); \
    unsigned short hl0_ = bfrn(hv0_ - bf2f(hh0_)), hl1_ = bfrn(hv1_ - bf2f(hh1_)); \
    *(unsigned short*)((char*)s_hh + (WB0)) = hh0_; \
    *(unsigned short*)((char*)s_hl + (WB0)) = hl0_; \
    *(unsigned short*)((char*)s_hh + (WB1)) = hh1_; \
    *(unsigned short*)((char*)s_hl + (WB1)) = hl1_; }

__global__ __launch_bounds__(512, 2) void lstm_mfma(
    const float*  __restrict__ ctx,    // [BS,SEQ,64]
    const bf16x8* __restrict__ whF,    // 16384 frags
    const bf16x8* __restrict__ wiFg,   // 8192 frags
    const float*  __restrict__ b_ih, const float* __restrict__ b_hh,
    const float*  __restrict__ W_out, const float* __restrict__ b_out,
    float* __restrict__ out)           // [BS,64]
{
    const int t  = threadIdx.x;
    const int w  = t >> 6, l = t & 63;
    const int lm = l & 15, lq = l >> 4;
    const int row0 = blockIdx.x * 8;            // 8 real rows per block

    __shared__ bf16x8 s_wi[8192];                       // 128 KB  W_ih frags
    __shared__ unsigned short s_xh[1024], s_xl[1024];   // [16][64] pair tile
    __shared__ unsigned short s_hh[4096], s_hl[4096];   // planes L(0B) H(4096B)

    for (int i = t; i < 8192; i += 512) s_wi[i] = wiFg[i];
    for (int i = t; i < 1024; i += 512) { s_xh[i] = 0; s_xl[i] = 0; }
    for (int i = t; i < 4096; i += 512) { s_hh[i] = 0; s_hl[i] = 0; }

    bf16x8 whr[4][4][2];
    #pragma unroll
    for (int ti = 0; ti < 4; ++ti)
        #pragma unroll
        for (int kc = 0; kc < 4; ++kc)
            #pragma unroll
            for (int p = 0; p < 2; ++p)
                whr[ti][kc][p] = whF[(((w * 4 + ti) * 4 + kc) * 2 + p) * 64 + l];

    const int m = w * 16 + lm;
    const float bi  = b_ih[m]       + b_hh[m];
    const float bff = b_ih[128 + m] + b_hh[128 + m];
    const float bg  = b_ih[256 + m] + b_hh[256 + m];
    const float bo  = b_ih[384 + m] + b_hh[384 + m];

    const int  urb  = ((lq & 1) << 2) | (lq & 2);
    const bool lolq = (lq < 2);
    float c20 = 0.f, c21 = 0.f;

    const int xrow  = t >> 5;
    const int xl32  = t & 31;
    const int srow  = xrow & 7;
    const int spair = xrow >> 3;
    const float2* ctx2 = (const float2*)ctx;
    const int xbase = (row0 + srow) * SEQ + spair;
    const int xwb   = xrow * 128 + ((4 * xl32) ^ ((xrow & 7) << 4));
    const int swzr  = (lm & 7) << 4;
    const int hwb_m = 32 * w + 2 * lm;
    const int wb0e = 4096 + (8 + urb) * 256 + (hwb_m ^ (urb << 4));
    const int wb1e = 4096 + (9 + urb) * 256 + (hwb_m ^ ((urb + 1) << 4));
    const int wb0o = urb * 256 + (hwb_m ^ (urb << 4));
    const int wb1o = (urb + 1) * 256 + (hwb_m ^ ((urb + 1) << 4));

    float2 xv = ctx2[xbase * 32 + xl32];

    for (int u = 0; u < SEQ / 2; ++u) {
        {   // stage x-pair (rows 0-7 = x(s0), rows 8-15 = x(s1))
            unsigned short xh0 = bfrn(xv.x), xh1 = bfrn(xv.y);
            unsigned short xl0 = bfrn(xv.x - bf2f(xh0)), xl1 = bfrn(xv.y - bf2f(xh1));
            *(unsigned int*)((char*)s_xh + xwb) = (unsigned int)xh0 | ((unsigned int)xh1 << 16);
            *(unsigned int*)((char*)s_xl + xwb) = (unsigned int)xl0 | ((unsigned int)xl1 << 16);
        }
        __syncthreads();   // x-pair + h(s0-1) (plane L) visible

        float2 xvn = make_float2(0.f, 0.f);
        if (u + 1 < SEQ / 2) xvn = ctx2[(xbase + 2 * u + 2) * 32 + xl32];

        bf16x8 hfh[4], hfl[4];
        if (u > 0) {
            #pragma unroll
            for (int kc = 0; kc < 4; ++kc) {
                int b = lm * 256 + ((kc * 64 + lq * 16) ^ swzr);   // plane L
                hfh[kc] = *(const bf16x8*)((const char*)s_hh + b);
                hfl[kc] = *(const bf16x8*)((const char*)s_hl + b);
            }
        }
        bf16x8 xfh[2], xfl[2];
        #pragma unroll
        for (int kc = 0; kc < 2; ++kc) {
            int b = lm * 128 + ((kc * 64 + lq * 16) ^ swzr);
            xfh[kc] = *(const bf16x8*)((const char*)s_xh + b);
            xfl[kc] = *(const bf16x8*)((const char*)s_xl + b);
        }

        f32x4 a0 = {0.f,0.f,0.f,0.f}, a1 = a0, a2 = a0, a3 = a0;

        if (u > 0) { HPASS }           // h(s0-1)W -> acc rows 0-7 only

        #pragma unroll                  // x-pass: both steps, junk-free
        for (int kc = 0; kc < 2; ++kc) {
            bf16x8 wihi[4], wilo[4];
            #pragma unroll
            for (int ti = 0; ti < 4; ++ti) {
                int base = (((w + 8 * ti) * 2 + kc) * 2) * 64 + l;
                wihi[ti] = s_wi[base];
                wilo[ti] = s_wi[base + 64];
            }
            MM4(xfh[kc], wihi[0], wihi[1], wihi[2], wihi[3])
            MM4(xfl[kc], wihi[0], wihi[1], wihi[2], wihi[3])
            MM4(xfh[kc], wilo[0], wilo[1], wilo[2], wilo[3])
        }

        {   // even pointwise: rows 0-7
            float gi0, gi1, gf0, gf1, gg0, gg1, go0, go1;
            REDIST_E(a0, gi0, gi1)
            REDIST_E(a1, gf0, gf1)
            REDIST_E(a2, gg0, gg1)
            REDIST_E(a3, go0, go1)
            PWBODY(gi0, gf0, gg0, go0, gi1, gf1, gg1, go1, wb0e, wb1e)
        }

        // ================= ODD step s1 = 2u+1 =================
        __syncthreads();   // h(s0) (plane H) visible
        #pragma unroll
        for (int kc = 0; kc < 4; ++kc) {
            int b = 4096 + lm * 256 + ((kc * 64 + lq * 16) ^ swzr);  // plane H
            hfh[kc] = *(const bf16x8*)((const char*)s_hh + b);
            hfl[kc] = *(const bf16x8*)((const char*)s_hl + b);
        }
        HPASS                          // h(s0)W -> acc rows 8-15 only

        {   // odd pointwise: rows 8-15
            float gi0, gi1, gf0, gf1, gg0, gg1, go0, go1;
            REDIST_O(a0, gi0, gi1)
            REDIST_O(a1, gf0, gf1)
            REDIST_O(a2, gg0, gg1)
            REDIST_O(a3, go0, go1)
            PWBODY(gi0, gf0, gg0, go0, gi1, gf1, gg1, go1, wb0o, wb1o)
        }
        xv = xvn;
    }
    __syncthreads();

    // ---- epilogue: h(SEQ-1)=h(49) is odd -> plane L rows 0-7 ----
    {
        const int row = t >> 5;
        if (row < 8) {
            const int j0 = t & 31, j1 = (t & 31) + 32;
            const int rswz = (row & 7) << 4;
            float accA = b_out[j0], accB = b_out[j1];
            #pragma unroll
            for (int kq = 0; kq < 16; ++kq) {
                int b = row * 256 + ((kq * 16) ^ rswz);
                bf16x8 hh8 = *(const bf16x8*)((const char*)s_hh + b);
                bf16x8 hl8 = *(const bf16x8*)((const char*)s_hl + b);
                #pragma unroll
                for (int e = 0; e < 8; ++e) {
                    float h = bf2f((unsigned short)hh8[e]) + bf2f((unsigned short)hl8[e]);
                    int k = kq * 8 + e;
                    accA = fmaf(h, W_out[j0 * 128 + k], accA);
                    accB = fmaf(h, W_out[j1 * 128 + k], accB);
                }
            }
            out[(row0 + row) * 64 + j0] = accA;
            out[(row0 + row) * 64 + j1] = accB;
        }
    }
}

// ---------------------------------------------------------------------------
extern "C" void kernel_launch(void* const* d_in, const int* in_sizes, int n_in,
                              void* d_out, int out_size, void* d_ws, size_t ws_size,
                              hipStream_t stream) {
    (void)in_sizes; (void)n_in; (void)out_size; (void)ws_size;
    const float* seqs  = (const float*)d_in[0];
    const float* ets   = (const float*)d_in[1];
    const int*   masks = (const int*)d_in[2];
    const float* Wf  = (const float*)d_in[3];
    const float* bf  = (const float*)d_in[4];
    const float* Wk  = (const float*)d_in[5];
    const float* bk  = (const float*)d_in[6];
    const float* Wq  = (const float*)d_in[7];
    const float* bq  = (const float*)d_in[8];
    const float* Wv  = (const float*)d_in[9];
    const float* bv  = (const float*)d_in[10];
    const float* Wih = (const float*)d_in[11];
    const float* Whh = (const float*)d_in[12];
    const float* bih = (const float*)d_in[13];
    const float* bhh = (const float*)d_in[14];
    const float* Wo  = (const float*)d_in[15];
    const float* bo  = (const float*)d_in[16];

    // ws layout: whF 256K | wiF 128K | ctx 26.2M  (attn tables in device globals)
    char* ws = (char*)d_ws;
    bf16x8* whF = (bf16x8*)(ws);
    bf16x8* wiF = (bf16x8*)(ws + 262144);
    float*  ctx = (float*) (ws + 262144 + 131072);

    hipLaunchKernelGGL(prep_all, dim3(52), dim3(512), 0, stream,
                       Wih, Whh, whF, wiF, Wf, bf, Wq, bq, Wv, Wk, bk);
    hipLaunchKernelGGL(edge_attn_ctx, dim3(4096), dim3(64), 0, stream,
                       seqs, ets, masks, bv, ctx);
    hipLaunchKernelGGL(lstm_mfma, dim3(256), dim3(512), 0, stream,
                       ctx, whF, wiF, bih, bhh, Wo, bo, (float*)d_out);
}

// Round 9
// 248.515 us; speedup vs baseline: 1.1700x; 1.1700x over previous
//
#include <hip/hip_runtime.h>
#include <math.h>

#define BS   2048
#define SEQ  50
#define NPOS (BS * SEQ)

typedef __attribute__((ext_vector_type(8))) short bf16x8;   // 8 bf16 = 4 VGPR
typedef __attribute__((ext_vector_type(4))) float f32x4;

__device__ __forceinline__ float sigf(float x) { return 1.0f / (1.0f + __expf(-x)); }
__device__ __forceinline__ float tanhfast(float x) {
    float e = __expf(2.0f * x);
    return 1.0f - 2.0f / (e + 1.0f);
}
__device__ __forceinline__ unsigned short bfrn(float x) {   // fp32 -> bf16 rne
    unsigned int u = __float_as_uint(x);
    u += 0x7FFFu + ((u >> 16) & 1u);
    return (unsigned short)(u >> 16);
}
__device__ __forceinline__ float bf2f(unsigned short h) {
    return __uint_as_float(((unsigned int)h) << 16);
}

#define FMA4(A, X, W) \
    A = fmaf((X).x, (W).x, A); A = fmaf((X).y, (W).y, A); \
    A = fmaf((X).z, (W).z, A); A = fmaf((X).w, (W).w, A);

// ---------------------------------------------------------------------------
// Precomputed attention tables (position-independent):
//   Wvf[64][10]: Wv . Wf(:,0:10)
//   Ce [64][9]:  (Wf(:,10+e)+bf) . Wv
//   Ag [4][10][7]: g_h[k] = Ag[h][k][0:6].self6 + Ag[h][k][6]
//   Bd [9][4][7]:  dd[e][h] = Bd[e][h][0:6].self6 + Bd[e][h][6]
// ---------------------------------------------------------------------------
__device__ float Wvf_d[640];
__device__ float Ce_d[576];
__device__ float Ag_d[280];
__device__ float Bd_d[252];

// ---------------------------------------------------------------------------
// prep (unchanged from R8 — two-stage Ag/Bd build, fast).
// ---------------------------------------------------------------------------
__global__ __launch_bounds__(512) void prep_all(
    const float* __restrict__ Wih, const float* __restrict__ Whh,
    bf16x8* __restrict__ whF, bf16x8* __restrict__ wiF,
    const float* __restrict__ Wf, const float* __restrict__ bf,
    const float* __restrict__ Wq, const float* __restrict__ bq,
    const float* __restrict__ Wv,
    const float* __restrict__ Wk, const float* __restrict__ bk)
{
    __shared__ float sG[640];   // G[n][k] = Wq[n,:].Wf[:,k]
    __shared__ float sD[576];   // D[e][n]

    if (blockIdx.x < 48) {
        int id = blockIdx.x * 512 + threadIdx.x;
        const float* src;
        bf16x8* dst;
        int p;
        if (id < 16384) {
            int l = id & 63, frag = id >> 6;        // 0..255
            p = frag & 1;
            int kc = (frag >> 1) & 3, ti = (frag >> 3) & 3, w = frag >> 5;
            int n  = (w + 8 * ti) * 16 + (l & 15);
            int k0 = kc * 32 + (l >> 4) * 8;
            src = &Whh[n * 128 + k0];
            dst = &whF[frag * 64 + l];
        } else {
            int id2 = id - 16384;
            int l = id2 & 63, frag = id2 >> 6;      // 0..127
            p = frag & 1;
            int kc = (frag >> 1) & 1, tile = frag >> 2;
            int n  = tile * 16 + (l & 15);
            int k0 = kc * 32 + (l >> 4) * 8;
            src = &Wih[n * 64 + k0];
            dst = &wiF[frag * 64 + l];
        }
        bf16x8 v;
        #pragma unroll
        for (int j = 0; j < 8; ++j) {
            float x = src[j];
            unsigned short hi = bfrn(x);
            unsigned short r  = p ? bfrn(x - bf2f(hi)) : hi;
            v[j] = (short)r;
        }
        *dst = v;
        return;
    }

    if (blockIdx.x < 51) {               // Wvf (640) + Ce (576), flat
        int i = (blockIdx.x - 48) * 512 + threadIdx.x;   // 0..1535
        if (i >= 1216) return;
        if (i < 640) {
            int o = i / 10, k = i % 10;
            float s = 0.f;
            #pragma unroll 8
            for (int j = 0; j < 64; ++j) s = fmaf(Wv[o * 64 + j], Wf[j * 19 + k], s);
            Wvf_d[i] = s;
        } else {
            int i2 = i - 640;
            int o = i2 / 9, e = i2 % 9;
            float s = 0.f;
            #pragma unroll 8
            for (int j = 0; j < 64; ++j)
                s = fmaf(Wf[j * 19 + 10 + e] + bf[j], Wv[o * 64 + j], s);
            Ce_d[i2] = s;
        }
        return;
    }

    // block 51: stage 1 — G and D into LDS
    const int t = threadIdx.x;
    for (int i = t; i < 1216; i += 512) {
        if (i < 640) {
            int n = i / 10, k = i % 10;
            float s = 0.f;
            #pragma unroll 8
            for (int j = 0; j < 64; ++j) s = fmaf(Wq[n * 64 + j], Wf[j * 19 + k], s);
            sG[i] = s;
        } else {
            int i2 = i - 640;
            int e = i2 >> 6, n = i2 & 63;
            float s = bq[n];
            #pragma unroll 8
            for (int j = 0; j < 64; ++j)
                s = fmaf(Wf[j * 19 + 10 + e] + bf[j], Wq[n * 64 + j], s);
            sD[i2] = s;
        }
    }
    __syncthreads();
    // stage 2 — fold with Wk/bk (16 FMA each)
    for (int i = t; i < 532; i += 512) {
        if (i < 280) {                   // Ag: i = (h*10+k)*7 + jj
            int h = i / 70, rem = i % 70, k = rem / 7, jj = rem % 7;
            float s = 0.f;
            #pragma unroll
            for (int d = 0; d < 16; ++d) {
                int n = h * 16 + d;
                float wkj = (jj < 6) ? Wk[n * 6 + jj] : bk[n];
                s = fmaf(wkj, sG[n * 10 + k], s);
            }
            Ag_d[i] = s;
        } else {                         // Bd: i4 = (e*4+h)*7 + jj
            int i4 = i - 280;
            int e = i4 / 28, rem = i4 % 28, h = rem / 7, jj = rem % 7;
            float s = 0.f;
            #pragma unroll
            for (int d = 0; d < 16; ++d) {
                int n = h * 16 + d;
                float wkj = (jj < 6) ? Wk[n * 6 + jj] : bk[n];
                s = fmaf(wkj, sD[e * 64 + n], s);
            }
            Bd_d[i4] = s;
        }
    }
}

// ---------------------------------------------------------------------------
// Kernel A v6: v4's proven LDS-phase structure, but TWO positions per wave
// interleaved (A = p, B = p+4096) with disjoint LDS buffers.  Each phase does
// A then B before the shared barrier: B's LDS round-trip issues while A's is
// in flight, and barriers halve per position (6 per 2 positions).  Serial
// iterations per wave drop 25 -> 12.5.  launch_bounds(64,4) caps VGPR at 128
// (R5's spill trap avoided).
// ---------------------------------------------------------------------------
__global__ __launch_bounds__(64, 4) void edge_attn_ctx(
    const float* __restrict__ seqs,   // [BS,SEQ,3,3,6]
    const float* __restrict__ ets,    // [BS,SEQ,3,3,4]
    const int*   __restrict__ masks,  // [BS,SEQ,3,3]
    const float* __restrict__ bv,
    float* __restrict__ ctx)          // [BS,SEQ,64]
{
    const int o   = threadIdx.x;
    const int h_o = o >> 4;
    const int lg  = (o < 40) ? o : 0;     // g/rbar lanes: (gh, gk)
    const int gh  = lg / 10, gk = lg % 10;
    const int la  = (o < 36) ? o : 0;     // att lanes: (ah, ae)
    const int ah  = la / 9,  ae = la % 9;

    float Agr[7], Bdr[7];
    #pragma unroll
    for (int q = 0; q < 7; ++q) Agr[q] = Ag_d[(gh * 10 + gk) * 7 + q];
    #pragma unroll
    for (int q = 0; q < 7; ++q) Bdr[q] = Bd_d[(ae * 4 + ah) * 7 + q];
    float Wvfr[10];
    #pragma unroll
    for (int k = 0; k < 10; ++k) Wvfr[k] = Wvf_d[o * 10 + k];
    const float bvr = bv[o];
    float Cer[9];
    #pragma unroll
    for (int e = 0; e < 9; ++e) Cer[e] = Ce_d[o * 9 + e] + bvr;

    __shared__ float sqA[54], seA[36], sgA[40], saA[36], sxA[36], srA[40];
    __shared__ float sqB[54], seB[36], sgB[40], saB[36], sxB[36], srB[40];
    __shared__ int   smA[9], smB[9];

    // prefetch iteration 0 (A = blockIdx, B = +4096)
    float rsA = 0.f, reA = 0.f, rsB = 0.f, reB = 0.f;
    int   rmA = 0, rmB = 0;
    {
        int pA = blockIdx.x, pB = pA + 4096;
        if (o < 54) rsA = seqs[pA * 54 + o];
        if (o < 36) reA = ets[pA * 36 + o];
        if (o < 9)  rmA = masks[pA * 9 + o];
        if (pB < NPOS) {
            if (o < 54) rsB = seqs[pB * 54 + o];
            if (o < 36) reB = ets[pB * 36 + o];
            if (o < 9)  rmB = masks[pB * 9 + o];
        }
    }

    for (int p = blockIdx.x; p < NPOS; p += 8192) {
        const int  pB  = p + 4096;
        const bool okB = pB < NPOS;

        // ---- stage both positions ----
        if (o < 54) { sqA[o] = rsA; sqB[o] = rsB; }
        if (o < 36) { seA[o] = reA; seB[o] = reB; }
        if (o < 9)  { smA[o] = rmA; smB[o] = rmB; }
        __syncthreads();

        // ---- issue next-iteration prefetch (spans 4 barriers) ----
        {
            int pn = p + 8192, pnB = pn + 4096;
            if (pn < NPOS) {
                if (o < 54) rsA = seqs[pn * 54 + o];
                if (o < 36) reA = ets[pn * 36 + o];
                if (o < 9)  rmA = masks[pn * 9 + o];
            }
            if (pnB < NPOS) {
                if (o < 54) rsB = seqs[pnB * 54 + o];
                if (o < 36) reB = ets[pnB * 36 + o];
                if (o < 9)  rmB = masks[pnB * 9 + o];
            }
        }

        // ---- phase 1: g (lanes<40) and dd (lanes<36), affine in self6 ----
        float ttA = 0.f, ttB = 0.f;
        {
            float a0 = sqA[24], a1 = sqA[25], a2 = sqA[26],
                  a3 = sqA[27], a4 = sqA[28], a5 = sqA[29];
            float b0 = sqB[24], b1 = sqB[25], b2 = sqB[26],
                  b3 = sqB[27], b4 = sqB[28], b5 = sqB[29];
            if (o < 40) {
                float gA = Agr[6], gB = Agr[6];
                gA = fmaf(a0, Agr[0], gA); gB = fmaf(b0, Agr[0], gB);
                gA = fmaf(a1, Agr[1], gA); gB = fmaf(b1, Agr[1], gB);
                gA = fmaf(a2, Agr[2], gA); gB = fmaf(b2, Agr[2], gB);
                gA = fmaf(a3, Agr[3], gA); gB = fmaf(b3, Agr[3], gB);
                gA = fmaf(a4, Agr[4], gA); gB = fmaf(b4, Agr[4], gB);
                gA = fmaf(a5, Agr[5], gA); gB = fmaf(b5, Agr[5], gB);
                sgA[o] = gA; sgB[o] = gB;
            }
            if (o < 36) {
                ttA = Bdr[6]; ttB = Bdr[6];
                ttA = fmaf(a0, Bdr[0], ttA); ttB = fmaf(b0, Bdr[0], ttB);
                ttA = fmaf(a1, Bdr[1], ttA); ttB = fmaf(b1, Bdr[1], ttB);
                ttA = fmaf(a2, Bdr[2], ttA); ttB = fmaf(b2, Bdr[2], ttB);
                ttA = fmaf(a3, Bdr[3], ttA); ttB = fmaf(b3, Bdr[3], ttB);
                ttA = fmaf(a4, Bdr[4], ttA); ttB = fmaf(b4, Bdr[4], ttB);
                ttA = fmaf(a5, Bdr[5], ttA); ttB = fmaf(b5, Bdr[5], ttB);
            }
        }
        __syncthreads();

        // ---- phase 2: att[e][h] (lanes<36) ----
        float aA = 0.f, aB = 0.f;
        if (o < 36) {
            aA = ttA; aB = ttB;
            #pragma unroll
            for (int k = 0; k < 6; ++k) {
                aA = fmaf(sqA[ae * 6 + k], sgA[ah * 10 + k], aA);
                aB = fmaf(sqB[ae * 6 + k], sgB[ah * 10 + k], aB);
            }
            #pragma unroll
            for (int k = 0; k < 4; ++k) {
                aA = fmaf(seA[ae * 4 + k], sgA[ah * 10 + 6 + k], aA);
                aB = fmaf(seB[ae * 4 + k], sgB[ah * 10 + 6 + k], aB);
            }
            aA *= 0.25f; aB *= 0.25f;
            if (smA[ae] == 0) aA = -1.0e10f;
            if (smB[ae] == 0) aB = -1.0e10f;
            saA[o] = aA; saB[o] = aB;
        }
        __syncthreads();

        // ---- phase 3: exp with per-head max (lanes<36) ----
        float exA = 0.f, exB = 0.f;
        if (o < 36) {
            float mxA = saA[ah * 9 + 0], mxB = saB[ah * 9 + 0];
            #pragma unroll
            for (int e = 1; e < 9; ++e) {
                mxA = fmaxf(mxA, saA[ah * 9 + e]);
                mxB = fmaxf(mxB, saB[ah * 9 + e]);
            }
            exA = __expf(aA - mxA); exB = __expf(aB - mxB);
            sxA[o] = exA; sxB[o] = exB;
        }
        __syncthreads();

        // ---- phase 4: rbar (lanes<40, unnormalized) ----
        if (o < 40) {
            float rbA = 0.f, rbB = 0.f;
            #pragma unroll
            for (int e = 0; e < 9; ++e) {
                float xA = (gk < 6) ? sqA[e * 6 + gk] : seA[e * 4 + (gk - 6)];
                float xB = (gk < 6) ? sqB[e * 6 + gk] : seB[e * 4 + (gk - 6)];
                rbA = fmaf(sxA[gh * 9 + e], xA, rbA);
                rbB = fmaf(sxB[gh * 9 + e], xB, rbB);
            }
            srA[o] = rbA; srB[o] = rbB;
        }
        __syncthreads();

        // ---- phase 5: ctx (all lanes); normalize at the end ----
        {
            float ssA = 0.f, ssB = 0.f;
            #pragma unroll
            for (int e = 0; e < 9; ++e) { ssA += sxA[h_o * 9 + e]; ssB += sxB[h_o * 9 + e]; }
            float acA = 0.f, acB = 0.f;
            #pragma unroll
            for (int k = 0; k < 10; ++k) {
                acA = fmaf(srA[h_o * 10 + k], Wvfr[k], acA);
                acB = fmaf(srB[h_o * 10 + k], Wvfr[k], acB);
            }
            #pragma unroll
            for (int e = 0; e < 9; ++e) {
                acA = fmaf(sxA[h_o * 9 + e], Cer[e], acA);
                acB = fmaf(sxB[h_o * 9 + e], Cer[e], acB);
            }
            ctx[p * 64 + o] = acA * (1.0f / ssA);
            if (okB) ctx[pB * 64 + o] = acB * (1.0f / ssB);
        }
        __syncthreads();
        // trailing barrier protects sq/se reads (phase 4) from next stage
    }
}

// ---------------------------------------------------------------------------
// Kernel C v12: pair-step MFMA LSTM (unchanged; 115-123 us).
// ---------------------------------------------------------------------------
#define MFMA16(A, B, C) __builtin_amdgcn_mfma_f32_16x16x32_bf16(A, B, C, 0, 0, 0)
#define MM4(F, W0, W1, W2, W3) \
    a0 = MFMA16(F, W0, a0); a1 = MFMA16(F, W1, a1); \
    a2 = MFMA16(F, W2, a2); a3 = MFMA16(F, W3, a3);

#define HPASS \
    MM4(hfh[0], whr[0][0][0], whr[1][0][0], whr[2][0][0], whr[3][0][0]) \
    MM4(hfh[1], whr[0][1][0], whr[1][1][0], whr[2][1][0], whr[3][1][0]) \
    MM4(hfh[2], whr[0][2][0], whr[1][2][0], whr[2][2][0], whr[3][2][0]) \
    MM4(hfh[3], whr[0][3][0], whr[1][3][0], whr[2][3][0], whr[3][3][0]) \
    MM4(hfl[0], whr[0][0][0], whr[1][0][0], whr[2][0][0], whr[3][0][0]) \
    MM4(hfl[1], whr[0][1][0], whr[1][1][0], whr[2][1][0], whr[3][1][0]) \
    MM4(hfl[2], whr[0][2][0], whr[1][2][0], whr[2][2][0], whr[3][2][0]) \
    MM4(hfl[3], whr[0][3][0], whr[1][3][0], whr[2][3][0], whr[3][3][0]) \
    MM4(hfh[0], whr[0][0][1], whr[1][0][1], whr[2][0][1], whr[3][0][1]) \
    MM4(hfh[1], whr[0][1][1], whr[1][1][1], whr[2][1][1], whr[3][1][1]) \
    MM4(hfh[2], whr[0][2][1], whr[1][2][1], whr[2][2][1], whr[3][2][1]) \
    MM4(hfh[3], whr[0][3][1], whr[1][3][1], whr[2][3][1], whr[3][3][1])

#define REDIST_E(ch, g0, g1) { \
    float s2_ = __shfl_xor(ch[2], 32), s3_ = __shfl_xor(ch[3], 32); \
    g0 = lolq ? ch[0] : s2_;  g1 = lolq ? ch[1] : s3_; }
#define REDIST_O(ch, g0, g1) { \
    float s0_ = __shfl_xor(ch[0], 32), s1_ = __shfl_xor(ch[1], 32); \
    g0 = lolq ? s0_ : ch[2];  g1 = lolq ? s1_ : ch[3]; }

#define PWBODY(gi0,gf0,gg0,go0,gi1,gf1,gg1,go1, WB0, WB1) { \
    float i0_ = sigf(gi0 + bi), f0_ = sigf(gf0 + bff); \
    float gA_ = tanhfast(gg0 + bg), o0_ = sigf(go0 + bo); \
    c20 = fmaf(f0_, c20, i0_ * gA_); \
    float hv0_ = o0_ * tanhfast(c20); \
    float i1_ = sigf(gi1 + bi), f1_ = sigf(gf1 + bff); \
    float gB_ = tanhfast(gg1 + bg), o1_ = sigf(go1 + bo); \
    c21 = fmaf(f1_, c21, i1_ * gB_); \
    float hv1_ = o1_ * tanhfast(c21); \
    unsigned short hh0_ = bfrn(hv0_), hh1_ = bfrn(hv1_); \
    unsigned short hl0_ = bfrn(hv0_ - bf2f(hh0_)), hl1_ = bfrn(hv1_ - bf2f(hh1_)); \
    *(unsigned short*)((char*)s_hh + (WB0)) = hh0_; \
    *(unsigned short*)((char*)s_hl + (WB0)) = hl0_; \
    *(unsigned short*)((char*)s_hh + (WB1)) = hh1_; \
    *(unsigned short*)((char*)s_hl + (WB1)) = hl1_; }

__global__ __launch_bounds__(512, 2) void lstm_mfma(
    const float*  __restrict__ ctx,    // [BS,SEQ,64]
    const bf16x8* __restrict__ whF,    // 16384 frags
    const bf16x8* __restrict__ wiFg,   // 8192 frags
    const float*  __restrict__ b_ih, const float* __restrict__ b_hh,
    const float*  __restrict__ W_out, const float* __restrict__ b_out,
    float* __restrict__ out)           // [BS,64]
{
    const int t  = threadIdx.x;
    const int w  = t >> 6, l = t & 63;
    const int lm = l & 15, lq = l >> 4;
    const int row0 = blockIdx.x * 8;            // 8 real rows per block

    __shared__ bf16x8 s_wi[8192];                       // 128 KB  W_ih frags
    __shared__ unsigned short s_xh[1024], s_xl[1024];   // [16][64] pair tile
    __shared__ unsigned short s_hh[4096], s_hl[4096];   // planes L(0B) H(4096B)

    for (int i = t; i < 8192; i += 512) s_wi[i] = wiFg[i];
    for (int i = t; i < 1024; i += 512) { s_xh[i] = 0; s_xl[i] = 0; }
    for (int i = t; i < 4096; i += 512) { s_hh[i] = 0; s_hl[i] = 0; }

    bf16x8 whr[4][4][2];
    #pragma unroll
    for (int ti = 0; ti < 4; ++ti)
        #pragma unroll
        for (int kc = 0; kc < 4; ++kc)
            #pragma unroll
            for (int p = 0; p < 2; ++p)
                whr[ti][kc][p] = whF[(((w * 4 + ti) * 4 + kc) * 2 + p) * 64 + l];

    const int m = w * 16 + lm;
    const float bi  = b_ih[m]       + b_hh[m];
    const float bff = b_ih[128 + m] + b_hh[128 + m];
    const float bg  = b_ih[256 + m] + b_hh[256 + m];
    const float bo  = b_ih[384 + m] + b_hh[384 + m];

    const int  urb  = ((lq & 1) << 2) | (lq & 2);
    const bool lolq = (lq < 2);
    float c20 = 0.f, c21 = 0.f;

    const int xrow  = t >> 5;
    const int xl32  = t & 31;
    const int srow  = xrow & 7;
    const int spair = xrow >> 3;
    const float2* ctx2 = (const float2*)ctx;
    const int xbase = (row0 + srow) * SEQ + spair;
    const int xwb   = xrow * 128 + ((4 * xl32) ^ ((xrow & 7) << 4));
    const int swzr  = (lm & 7) << 4;
    const int hwb_m = 32 * w + 2 * lm;
    const int wb0e = 4096 + (8 + urb) * 256 + (hwb_m ^ (urb << 4));
    const int wb1e = 4096 + (9 + urb) * 256 + (hwb_m ^ ((urb + 1) << 4));
    const int wb0o = urb * 256 + (hwb_m ^ (urb << 4));
    const int wb1o = (urb + 1) * 256 + (hwb_m ^ ((urb + 1) << 4));

    float2 xv = ctx2[xbase * 32 + xl32];

    for (int u = 0; u < SEQ / 2; ++u) {
        {   // stage x-pair (rows 0-7 = x(s0), rows 8-15 = x(s1))
            unsigned short xh0 = bfrn(xv.x), xh1 = bfrn(xv.y);
            unsigned short xl0 = bfrn(xv.x - bf2f(xh0)), xl1 = bfrn(xv.y - bf2f(xh1));
            *(unsigned int*)((char*)s_xh + xwb) = (unsigned int)xh0 | ((unsigned int)xh1 << 16);
            *(unsigned int*)((char*)s_xl + xwb) = (unsigned int)xl0 | ((unsigned int)xl1 << 16);
        }
        __syncthreads();   // x-pair + h(s0-1) (plane L) visible

        float2 xvn = make_float2(0.f, 0.f);
        if (u + 1 < SEQ / 2) xvn = ctx2[(xbase + 2 * u + 2) * 32 + xl32];

        bf16x8 hfh[4], hfl[4];
        if (u > 0) {
            #pragma unroll
            for (int kc = 0; kc < 4; ++kc) {
                int b = lm * 256 + ((kc * 64 + lq * 16) ^ swzr);   // plane L
                hfh[kc] = *(const bf16x8*)((const char*)s_hh + b);
                hfl[kc] = *(const bf16x8*)((const char*)s_hl + b);
            }
        }
        bf16x8 xfh[2], xfl[2];
        #pragma unroll
        for (int kc = 0; kc < 2; ++kc) {
            int b = lm * 128 + ((kc * 64 + lq * 16) ^ swzr);
            xfh[kc] = *(const bf16x8*)((const char*)s_xh + b);
            xfl[kc] = *(const bf16x8*)((const char*)s_xl + b);
        }

        f32x4 a0 = {0.f,0.f,0.f,0.f}, a1 = a0, a2 = a0, a3 = a0;

        if (u > 0) { HPASS }           // h(s0-1)W -> acc rows 0-7 only

        #pragma unroll                  // x-pass: both steps, junk-free
        for (int kc = 0; kc < 2; ++kc) {
            bf16x8 wihi[4], wilo[4];
            #pragma unroll
            for (int ti = 0; ti < 4; ++ti) {
                int base = (((w + 8 * ti) * 2 + kc) * 2) * 64 + l;
                wihi[ti] = s_wi[base];
                wilo[ti] = s_wi[base + 64];
            }
            MM4(xfh[kc], wihi[0], wihi[1], wihi[2], wihi[3])
            MM4(xfl[kc], wihi[0], wihi[1], wihi[2], wihi[3])
            MM4(xfh[kc], wilo[0], wilo[1], wilo[2], wilo[3])
        }

        {   // even pointwise: rows 0-7
            float gi0, gi1, gf0, gf1, gg0, gg1, go0, go1;
            REDIST_E(a0, gi0, gi1)
            REDIST_E(a1, gf0, gf1)
            REDIST_E(a2, gg0, gg1)
            REDIST_E(a3, go0, go1)
            PWBODY(gi0, gf0, gg0, go0, gi1, gf1, gg1, go1, wb0e, wb1e)
        }

        // ================= ODD step s1 = 2u+1 =================
        __syncthreads();   // h(s0) (plane H) visible
        #pragma unroll
        for (int kc = 0; kc < 4; ++kc) {
            int b = 4096 + lm * 256 + ((kc * 64 + lq * 16) ^ swzr);  // plane H
            hfh[kc] = *(const bf16x8*)((const char*)s_hh + b);
            hfl[kc] = *(const bf16x8*)((const char*)s_hl + b);
        }
        HPASS                          // h(s0)W -> acc rows 8-15 only

        {   // odd pointwise: rows 8-15
            float gi0, gi1, gf0, gf1, gg0, gg1, go0, go1;
            REDIST_O(a0, gi0, gi1)
            REDIST_O(a1, gf0, gf1)
            REDIST_O(a2, gg0, gg1)
            REDIST_O(a3, go0, go1)
            PWBODY(gi0, gf0, gg0, go0, gi1, gf1, gg1, go1, wb0o, wb1o)
        }
        xv = xvn;
    }
    __syncthreads();

    // ---- epilogue: h(SEQ-1)=h(49) is odd -> plane L rows 0-7 ----
    {
        const int row = t >> 5;
        if (row < 8) {
            const int j0 = t & 31, j1 = (t & 31) + 32;
            const int rswz = (row & 7) << 4;
            float accA = b_out[j0], accB = b_out[j1];
            #pragma unroll
            for (int kq = 0; kq < 16; ++kq) {
                int b = row * 256 + ((kq * 16) ^ rswz);
                bf16x8 hh8 = *(const bf16x8*)((const char*)s_hh + b);
                bf16x8 hl8 = *(const bf16x8*)((const char*)s_hl + b);
                #pragma unroll
                for (int e = 0; e < 8; ++e) {
                    float h = bf2f((unsigned short)hh8[e]) + bf2f((unsigned short)hl8[e]);
                    int k = kq * 8 + e;
                    accA = fmaf(h, W_out[j0 * 128 + k], accA);
                    accB = fmaf(h, W_out[j1 * 128 + k], accB);
                }
            }
            out[(row0 + row) * 64 + j0] = accA;
            out[(row0 + row) * 64 + j1] = accB;
        }
    }
}

// ---------------------------------------------------------------------------
extern "C" void kernel_launch(void* const* d_in, const int* in_sizes, int n_in,
                              void* d_out, int out_size, void* d_ws, size_t ws_size,
                              hipStream_t stream) {
    (void)in_sizes; (void)n_in; (void)out_size; (void)ws_size;
    const float* seqs  = (const float*)d_in[0];
    const float* ets   = (const float*)d_in[1];
    const int*   masks = (const int*)d_in[2];
    const float* Wf  = (const float*)d_in[3];
    const float* bf  = (const float*)d_in[4];
    const float* Wk  = (const float*)d_in[5];
    const float* bk  = (const float*)d_in[6];
    const float* Wq  = (const float*)d_in[7];
    const float* bq  = (const float*)d_in[8];
    const float* Wv  = (const float*)d_in[9];
    const float* bv  = (const float*)d_in[10];
    const float* Wih = (const float*)d_in[11];
    const float* Whh = (const float*)d_in[12];
    const float* bih = (const float*)d_in[13];
    const float* bhh = (const float*)d_in[14];
    const float* Wo  = (const float*)d_in[15];
    const float* bo  = (const float*)d_in[16];

    // ws layout: whF 256K | wiF 128K | ctx 26.2M  (attn tables in device globals)
    char* ws = (char*)d_ws;
    bf16x8* whF = (bf16x8*)(ws);
    bf16x8* wiF = (bf16x8*)(ws + 262144);
    float*  ctx = (float*) (ws + 262144 + 131072);

    hipLaunchKernelGGL(prep_all, dim3(52), dim3(512), 0, stream,
                       Wih, Whh, whF, wiF, Wf, bf, Wq, bq, Wv, Wk, bk);
    hipLaunchKernelGGL(edge_attn_ctx, dim3(4096), dim3(64), 0, stream,
                       seqs, ets, masks, bv, ctx);
    hipLaunchKernelGGL(lstm_mfma, dim3(256), dim3(512), 0, stream,
                       ctx, whF, wiF, bih, bhh, Wo, bo, (float*)d_out);
}

// Round 10
// 245.798 us; speedup vs baseline: 1.1830x; 1.0111x over previous
//
#include <hip/hip_runtime.h>
#include <math.h>

#define BS   2048
#define SEQ  50
#define NPOS (BS * SEQ)

typedef __attribute__((ext_vector_type(8))) short bf16x8;   // 8 bf16 = 4 VGPR
typedef __attribute__((ext_vector_type(4))) float f32x4;

__device__ __forceinline__ float sigf(float x) { return 1.0f / (1.0f + __expf(-x)); }
__device__ __forceinline__ float tanhfast(float x) {
    float e = __expf(2.0f * x);
    return 1.0f - 2.0f / (e + 1.0f);
}
__device__ __forceinline__ unsigned short bfrn(float x) {   // fp32 -> bf16 rne
    unsigned int u = __float_as_uint(x);
    u += 0x7FFFu + ((u >> 16) & 1u);
    return (unsigned short)(u >> 16);
}
__device__ __forceinline__ float bf2f(unsigned short h) {
    return __uint_as_float(((unsigned int)h) << 16);
}

#define FMA4(A, X, W) \
    A = fmaf((X).x, (W).x, A); A = fmaf((X).y, (W).y, A); \
    A = fmaf((X).z, (W).z, A); A = fmaf((X).w, (W).w, A);

// ---------------------------------------------------------------------------
// Precomputed attention tables (position-independent):
//   Wvf[64][10]: Wv . Wf(:,0:10)
//   Ce [64][9]:  (Wf(:,10+e)+bf) . Wv
//   Ag [4][10][7]: g_h[k] = Ag[h][k][0:6].self6 + Ag[h][k][6]
//   Bd [9][4][7]:  dd[e][h] = Bd[e][h][0:6].self6 + Bd[e][h][6]
// ---------------------------------------------------------------------------
__device__ float Wvf_d[640];
__device__ float Ce_d[576];
__device__ float Ag_d[280];
__device__ float Bd_d[252];

// ---------------------------------------------------------------------------
// prep (unchanged — two-stage Ag/Bd build, fast).
// ---------------------------------------------------------------------------
__global__ __launch_bounds__(512) void prep_all(
    const float* __restrict__ Wih, const float* __restrict__ Whh,
    bf16x8* __restrict__ whF, bf16x8* __restrict__ wiF,
    const float* __restrict__ Wf, const float* __restrict__ bf,
    const float* __restrict__ Wq, const float* __restrict__ bq,
    const float* __restrict__ Wv,
    const float* __restrict__ Wk, const float* __restrict__ bk)
{
    __shared__ float sG[640];   // G[n][k] = Wq[n,:].Wf[:,k]
    __shared__ float sD[576];   // D[e][n]

    if (blockIdx.x < 48) {
        int id = blockIdx.x * 512 + threadIdx.x;
        const float* src;
        bf16x8* dst;
        int p;
        if (id < 16384) {
            int l = id & 63, frag = id >> 6;        // 0..255
            p = frag & 1;
            int kc = (frag >> 1) & 3, ti = (frag >> 3) & 3, w = frag >> 5;
            int n  = (w + 8 * ti) * 16 + (l & 15);
            int k0 = kc * 32 + (l >> 4) * 8;
            src = &Whh[n * 128 + k0];
            dst = &whF[frag * 64 + l];
        } else {
            int id2 = id - 16384;
            int l = id2 & 63, frag = id2 >> 6;      // 0..127
            p = frag & 1;
            int kc = (frag >> 1) & 1, tile = frag >> 2;
            int n  = tile * 16 + (l & 15);
            int k0 = kc * 32 + (l >> 4) * 8;
            src = &Wih[n * 64 + k0];
            dst = &wiF[frag * 64 + l];
        }
        bf16x8 v;
        #pragma unroll
        for (int j = 0; j < 8; ++j) {
            float x = src[j];
            unsigned short hi = bfrn(x);
            unsigned short r  = p ? bfrn(x - bf2f(hi)) : hi;
            v[j] = (short)r;
        }
        *dst = v;
        return;
    }

    if (blockIdx.x < 51) {               // Wvf (640) + Ce (576), flat
        int i = (blockIdx.x - 48) * 512 + threadIdx.x;   // 0..1535
        if (i >= 1216) return;
        if (i < 640) {
            int o = i / 10, k = i % 10;
            float s = 0.f;
            #pragma unroll 8
            for (int j = 0; j < 64; ++j) s = fmaf(Wv[o * 64 + j], Wf[j * 19 + k], s);
            Wvf_d[i] = s;
        } else {
            int i2 = i - 640;
            int o = i2 / 9, e = i2 % 9;
            float s = 0.f;
            #pragma unroll 8
            for (int j = 0; j < 64; ++j)
                s = fmaf(Wf[j * 19 + 10 + e] + bf[j], Wv[o * 64 + j], s);
            Ce_d[i2] = s;
        }
        return;
    }

    // block 51: stage 1 — G and D into LDS
    const int t = threadIdx.x;
    for (int i = t; i < 1216; i += 512) {
        if (i < 640) {
            int n = i / 10, k = i % 10;
            float s = 0.f;
            #pragma unroll 8
            for (int j = 0; j < 64; ++j) s = fmaf(Wq[n * 64 + j], Wf[j * 19 + k], s);
            sG[i] = s;
        } else {
            int i2 = i - 640;
            int e = i2 >> 6, n = i2 & 63;
            float s = bq[n];
            #pragma unroll 8
            for (int j = 0; j < 64; ++j)
                s = fmaf(Wf[j * 19 + 10 + e] + bf[j], Wq[n * 64 + j], s);
            sD[i2] = s;
        }
    }
    __syncthreads();
    // stage 2 — fold with Wk/bk (16 FMA each)
    for (int i = t; i < 532; i += 512) {
        if (i < 280) {                   // Ag: i = (h*10+k)*7 + jj
            int h = i / 70, rem = i % 70, k = rem / 7, jj = rem % 7;
            float s = 0.f;
            #pragma unroll
            for (int d = 0; d < 16; ++d) {
                int n = h * 16 + d;
                float wkj = (jj < 6) ? Wk[n * 6 + jj] : bk[n];
                s = fmaf(wkj, sG[n * 10 + k], s);
            }
            Ag_d[i] = s;
        } else {                         // Bd: i4 = (e*4+h)*7 + jj
            int i4 = i - 280;
            int e = i4 / 28, rem = i4 % 28, h = rem / 7, jj = rem % 7;
            float s = 0.f;
            #pragma unroll
            for (int d = 0; d < 16; ++d) {
                int n = h * 16 + d;
                float wkj = (jj < 6) ? Wk[n * 6 + jj] : bk[n];
                s = fmaf(wkj, sD[e * 64 + n], s);
            }
            Bd_d[i4] = s;
        }
    }
}

// ---------------------------------------------------------------------------
// Kernel A v6: two-position interleaved LDS-phase attention (unchanged).
// ---------------------------------------------------------------------------
__global__ __launch_bounds__(64, 4) void edge_attn_ctx(
    const float* __restrict__ seqs,   // [BS,SEQ,3,3,6]
    const float* __restrict__ ets,    // [BS,SEQ,3,3,4]
    const int*   __restrict__ masks,  // [BS,SEQ,3,3]
    const float* __restrict__ bv,
    float* __restrict__ ctx)          // [BS,SEQ,64]
{
    const int o   = threadIdx.x;
    const int h_o = o >> 4;
    const int lg  = (o < 40) ? o : 0;     // g/rbar lanes: (gh, gk)
    const int gh  = lg / 10, gk = lg % 10;
    const int la  = (o < 36) ? o : 0;     // att lanes: (ah, ae)
    const int ah  = la / 9,  ae = la % 9;

    float Agr[7], Bdr[7];
    #pragma unroll
    for (int q = 0; q < 7; ++q) Agr[q] = Ag_d[(gh * 10 + gk) * 7 + q];
    #pragma unroll
    for (int q = 0; q < 7; ++q) Bdr[q] = Bd_d[(ae * 4 + ah) * 7 + q];
    float Wvfr[10];
    #pragma unroll
    for (int k = 0; k < 10; ++k) Wvfr[k] = Wvf_d[o * 10 + k];
    const float bvr = bv[o];
    float Cer[9];
    #pragma unroll
    for (int e = 0; e < 9; ++e) Cer[e] = Ce_d[o * 9 + e] + bvr;

    __shared__ float sqA[54], seA[36], sgA[40], saA[36], sxA[36], srA[40];
    __shared__ float sqB[54], seB[36], sgB[40], saB[36], sxB[36], srB[40];
    __shared__ int   smA[9], smB[9];

    float rsA = 0.f, reA = 0.f, rsB = 0.f, reB = 0.f;
    int   rmA = 0, rmB = 0;
    {
        int pA = blockIdx.x, pB = pA + 4096;
        if (o < 54) rsA = seqs[pA * 54 + o];
        if (o < 36) reA = ets[pA * 36 + o];
        if (o < 9)  rmA = masks[pA * 9 + o];
        if (pB < NPOS) {
            if (o < 54) rsB = seqs[pB * 54 + o];
            if (o < 36) reB = ets[pB * 36 + o];
            if (o < 9)  rmB = masks[pB * 9 + o];
        }
    }

    for (int p = blockIdx.x; p < NPOS; p += 8192) {
        const int  pB  = p + 4096;
        const bool okB = pB < NPOS;

        if (o < 54) { sqA[o] = rsA; sqB[o] = rsB; }
        if (o < 36) { seA[o] = reA; seB[o] = reB; }
        if (o < 9)  { smA[o] = rmA; smB[o] = rmB; }
        __syncthreads();

        {
            int pn = p + 8192, pnB = pn + 4096;
            if (pn < NPOS) {
                if (o < 54) rsA = seqs[pn * 54 + o];
                if (o < 36) reA = ets[pn * 36 + o];
                if (o < 9)  rmA = masks[pn * 9 + o];
            }
            if (pnB < NPOS) {
                if (o < 54) rsB = seqs[pnB * 54 + o];
                if (o < 36) reB = ets[pnB * 36 + o];
                if (o < 9)  rmB = masks[pnB * 9 + o];
            }
        }

        float ttA = 0.f, ttB = 0.f;
        {
            float a0 = sqA[24], a1 = sqA[25], a2 = sqA[26],
                  a3 = sqA[27], a4 = sqA[28], a5 = sqA[29];
            float b0 = sqB[24], b1 = sqB[25], b2 = sqB[26],
                  b3 = sqB[27], b4 = sqB[28], b5 = sqB[29];
            if (o < 40) {
                float gA = Agr[6], gB = Agr[6];
                gA = fmaf(a0, Agr[0], gA); gB = fmaf(b0, Agr[0], gB);
                gA = fmaf(a1, Agr[1], gA); gB = fmaf(b1, Agr[1], gB);
                gA = fmaf(a2, Agr[2], gA); gB = fmaf(b2, Agr[2], gB);
                gA = fmaf(a3, Agr[3], gA); gB = fmaf(b3, Agr[3], gB);
                gA = fmaf(a4, Agr[4], gA); gB = fmaf(b4, Agr[4], gB);
                gA = fmaf(a5, Agr[5], gA); gB = fmaf(b5, Agr[5], gB);
                sgA[o] = gA; sgB[o] = gB;
            }
            if (o < 36) {
                ttA = Bdr[6]; ttB = Bdr[6];
                ttA = fmaf(a0, Bdr[0], ttA); ttB = fmaf(b0, Bdr[0], ttB);
                ttA = fmaf(a1, Bdr[1], ttA); ttB = fmaf(b1, Bdr[1], ttB);
                ttA = fmaf(a2, Bdr[2], ttA); ttB = fmaf(b2, Bdr[2], ttB);
                ttA = fmaf(a3, Bdr[3], ttA); ttB = fmaf(b3, Bdr[3], ttB);
                ttA = fmaf(a4, Bdr[4], ttA); ttB = fmaf(b4, Bdr[4], ttB);
                ttA = fmaf(a5, Bdr[5], ttA); ttB = fmaf(b5, Bdr[5], ttB);
            }
        }
        __syncthreads();

        float aA = 0.f, aB = 0.f;
        if (o < 36) {
            aA = ttA; aB = ttB;
            #pragma unroll
            for (int k = 0; k < 6; ++k) {
                aA = fmaf(sqA[ae * 6 + k], sgA[ah * 10 + k], aA);
                aB = fmaf(sqB[ae * 6 + k], sgB[ah * 10 + k], aB);
            }
            #pragma unroll
            for (int k = 0; k < 4; ++k) {
                aA = fmaf(seA[ae * 4 + k], sgA[ah * 10 + 6 + k], aA);
                aB = fmaf(seB[ae * 4 + k], sgB[ah * 10 + 6 + k], aB);
            }
            aA *= 0.25f; aB *= 0.25f;
            if (smA[ae] == 0) aA = -1.0e10f;
            if (smB[ae] == 0) aB = -1.0e10f;
            saA[o] = aA; saB[o] = aB;
        }
        __syncthreads();

        float exA = 0.f, exB = 0.f;
        if (o < 36) {
            float mxA = saA[ah * 9 + 0], mxB = saB[ah * 9 + 0];
            #pragma unroll
            for (int e = 1; e < 9; ++e) {
                mxA = fmaxf(mxA, saA[ah * 9 + e]);
                mxB = fmaxf(mxB, saB[ah * 9 + e]);
            }
            exA = __expf(aA - mxA); exB = __expf(aB - mxB);
            sxA[o] = exA; sxB[o] = exB;
        }
        __syncthreads();

        if (o < 40) {
            float rbA = 0.f, rbB = 0.f;
            #pragma unroll
            for (int e = 0; e < 9; ++e) {
                float xA = (gk < 6) ? sqA[e * 6 + gk] : seA[e * 4 + (gk - 6)];
                float xB = (gk < 6) ? sqB[e * 6 + gk] : seB[e * 4 + (gk - 6)];
                rbA = fmaf(sxA[gh * 9 + e], xA, rbA);
                rbB = fmaf(sxB[gh * 9 + e], xB, rbB);
            }
            srA[o] = rbA; srB[o] = rbB;
        }
        __syncthreads();

        {
            float ssA = 0.f, ssB = 0.f;
            #pragma unroll
            for (int e = 0; e < 9; ++e) { ssA += sxA[h_o * 9 + e]; ssB += sxB[h_o * 9 + e]; }
            float acA = 0.f, acB = 0.f;
            #pragma unroll
            for (int k = 0; k < 10; ++k) {
                acA = fmaf(srA[h_o * 10 + k], Wvfr[k], acA);
                acB = fmaf(srB[h_o * 10 + k], Wvfr[k], acB);
            }
            #pragma unroll
            for (int e = 0; e < 9; ++e) {
                acA = fmaf(sxA[h_o * 9 + e], Cer[e], acA);
                acB = fmaf(sxB[h_o * 9 + e], Cer[e], acB);
            }
            ctx[p * 64 + o] = acA * (1.0f / ssA);
            if (okB) ctx[pB * 64 + o] = acB * (1.0f / ssB);
        }
        __syncthreads();
    }
}

// ---------------------------------------------------------------------------
// Kernel C v13: pair-step MFMA LSTM with ALL weights in registers.
//  - W_ih frags move LDS -> registers (wir, 64 VGPR): each wave only ever
//    read its own 16 frags, so the 128 KB s_wi bought zero sharing and cost
//    16 of the 36 ds_read_b128 per wave per step (LDS pipe was the wall:
//    ~500 LDS-cyc/wave/step x 8 waves vs ~3300-cyc step time).
//  - LDS drops 151.5 KB -> 20.5 KB; VGPR 116 -> ~180 (budget 256 @ 2 w/EU).
// ---------------------------------------------------------------------------
#define MFMA16(A, B, C) __builtin_amdgcn_mfma_f32_16x16x32_bf16(A, B, C, 0, 0, 0)
#define MM4(F, W0, W1, W2, W3) \
    a0 = MFMA16(F, W0, a0); a1 = MFMA16(F, W1, a1); \
    a2 = MFMA16(F, W2, a2); a3 = MFMA16(F, W3, a3);

#define HPASS \
    MM4(hfh[0], whr[0][0][0], whr[1][0][0], whr[2][0][0], whr[3][0][0]) \
    MM4(hfh[1], whr[0][1][0], whr[1][1][0], whr[2][1][0], whr[3][1][0]) \
    MM4(hfh[2], whr[0][2][0], whr[1][2][0], whr[2][2][0], whr[3][2][0]) \
    MM4(hfh[3], whr[0][3][0], whr[1][3][0], whr[2][3][0], whr[3][3][0]) \
    MM4(hfl[0], whr[0][0][0], whr[1][0][0], whr[2][0][0], whr[3][0][0]) \
    MM4(hfl[1], whr[0][1][0], whr[1][1][0], whr[2][1][0], whr[3][1][0]) \
    MM4(hfl[2], whr[0][2][0], whr[1][2][0], whr[2][2][0], whr[3][2][0]) \
    MM4(hfl[3], whr[0][3][0], whr[1][3][0], whr[2][3][0], whr[3][3][0]) \
    MM4(hfh[0], whr[0][0][1], whr[1][0][1], whr[2][0][1], whr[3][0][1]) \
    MM4(hfh[1], whr[0][1][1], whr[1][1][1], whr[2][1][1], whr[3][1][1]) \
    MM4(hfh[2], whr[0][2][1], whr[1][2][1], whr[2][2][1], whr[3][2][1]) \
    MM4(hfh[3], whr[0][3][1], whr[1][3][1], whr[2][3][1], whr[3][3][1])

#define REDIST_E(ch, g0, g1) { \
    float s2_ = __shfl_xor(ch[2], 32), s3_ = __shfl_xor(ch[3], 32); \
    g0 = lolq ? ch[0] : s2_;  g1 = lolq ? ch[1] : s3_; }
#define REDIST_O(ch, g0, g1) { \
    float s0_ = __shfl_xor(ch[0], 32), s1_ = __shfl_xor(ch[1], 32); \
    g0 = lolq ? s0_ : ch[2];  g1 = lolq ? s1_ : ch[3]; }

#define PWBODY(gi0,gf0,gg0,go0,gi1,gf1,gg1,go1, WB0, WB1) { \
    float i0_ = sigf(gi0 + bi), f0_ = sigf(gf0 + bff); \
    float gA_ = tanhfast(gg0 + bg), o0_ = sigf(go0 + bo); \
    c20 = fmaf(f0_, c20, i0_ * gA_); \
    float hv0_ = o0_ * tanhfast(c20); \
    float i1_ = sigf(gi1 + bi), f1_ = sigf(gf1 + bff); \
    float gB_ = tanhfast(gg1 + bg), o1_ = sigf(go1 + bo); \
    c21 = fmaf(f1_, c21, i1_ * gB_); \
    float hv1_ = o1_ * tanhfast(c21); \
    unsigned short hh0_ = bfrn(hv0_), hh1_ = bfrn(hv1_); \
    unsigned short hl0_ = bfrn(hv0_ - bf2f(hh0_)), hl1_ = bfrn(hv1_ - bf2f(hh1_)); \
    *(unsigned short*)((char*)s_hh + (WB0)) = hh0_; \
    *(unsigned short*)((char*)s_hl + (WB0)) = hl0_; \
    *(unsigned short*)((char*)s_hh + (WB1)) = hh1_; \
    *(unsigned short*)((char*)s_hl + (WB1)) = hl1_; }

__global__ __launch_bounds__(512, 2) void lstm_mfma(
    const float*  __restrict__ ctx,    // [BS,SEQ,64]
    const bf16x8* __restrict__ whF,    // 16384 frags
    const bf16x8* __restrict__ wiFg,   // 8192 frags
    const float*  __restrict__ b_ih, const float* __restrict__ b_hh,
    const float*  __restrict__ W_out, const float* __restrict__ b_out,
    float* __restrict__ out)           // [BS,64]
{
    const int t  = threadIdx.x;
    const int w  = t >> 6, l = t & 63;
    const int lm = l & 15, lq = l >> 4;
    const int row0 = blockIdx.x * 8;            // 8 real rows per block

    __shared__ unsigned short s_xh[1024], s_xl[1024];   // [16][64] pair tile
    __shared__ unsigned short s_hh[4096], s_hl[4096];   // planes L(0B) H(4096B)

    for (int i = t; i < 1024; i += 512) { s_xh[i] = 0; s_xl[i] = 0; }
    for (int i = t; i < 4096; i += 512) { s_hh[i] = 0; s_hl[i] = 0; }

    // W_hh fragments (hi+lo) -> registers (128 VGPR)
    bf16x8 whr[4][4][2];
    #pragma unroll
    for (int ti = 0; ti < 4; ++ti)
        #pragma unroll
        for (int kc = 0; kc < 4; ++kc)
            #pragma unroll
            for (int p = 0; p < 2; ++p)
                whr[ti][kc][p] = whF[(((w * 4 + ti) * 4 + kc) * 2 + p) * 64 + l];

    // W_ih fragments (hi+lo) -> registers (64 VGPR); wave reads only its own
    bf16x8 wir[2][4][2];
    #pragma unroll
    for (int kc = 0; kc < 2; ++kc)
        #pragma unroll
        for (int ti = 0; ti < 4; ++ti)
            #pragma unroll
            for (int p = 0; p < 2; ++p)
                wir[kc][ti][p] = wiFg[(((w + 8 * ti) * 2 + kc) * 2 + p) * 64 + l];

    const int m = w * 16 + lm;
    const float bi  = b_ih[m]       + b_hh[m];
    const float bff = b_ih[128 + m] + b_hh[128 + m];
    const float bg  = b_ih[256 + m] + b_hh[256 + m];
    const float bo  = b_ih[384 + m] + b_hh[384 + m];

    const int  urb  = ((lq & 1) << 2) | (lq & 2);
    const bool lolq = (lq < 2);
    float c20 = 0.f, c21 = 0.f;

    const int xrow  = t >> 5;
    const int xl32  = t & 31;
    const int srow  = xrow & 7;
    const int spair = xrow >> 3;
    const float2* ctx2 = (const float2*)ctx;
    const int xbase = (row0 + srow) * SEQ + spair;
    const int xwb   = xrow * 128 + ((4 * xl32) ^ ((xrow & 7) << 4));
    const int swzr  = (lm & 7) << 4;
    const int hwb_m = 32 * w + 2 * lm;
    const int wb0e = 4096 + (8 + urb) * 256 + (hwb_m ^ (urb << 4));
    const int wb1e = 4096 + (9 + urb) * 256 + (hwb_m ^ ((urb + 1) << 4));
    const int wb0o = urb * 256 + (hwb_m ^ (urb << 4));
    const int wb1o = (urb + 1) * 256 + (hwb_m ^ ((urb + 1) << 4));

    float2 xv = ctx2[xbase * 32 + xl32];

    for (int u = 0; u < SEQ / 2; ++u) {
        {   // stage x-pair (rows 0-7 = x(s0), rows 8-15 = x(s1))
            unsigned short xh0 = bfrn(xv.x), xh1 = bfrn(xv.y);
            unsigned short xl0 = bfrn(xv.x - bf2f(xh0)), xl1 = bfrn(xv.y - bf2f(xh1));
            *(unsigned int*)((char*)s_xh + xwb) = (unsigned int)xh0 | ((unsigned int)xh1 << 16);
            *(unsigned int*)((char*)s_xl + xwb) = (unsigned int)xl0 | ((unsigned int)xl1 << 16);
        }
        __syncthreads();   // x-pair + h(s0-1) (plane L) visible

        float2 xvn = make_float2(0.f, 0.f);
        if (u + 1 < SEQ / 2) xvn = ctx2[(xbase + 2 * u + 2) * 32 + xl32];

        bf16x8 hfh[4], hfl[4];
        if (u > 0) {
            #pragma unroll
            for (int kc = 0; kc < 4; ++kc) {
                int b = lm * 256 + ((kc * 64 + lq * 16) ^ swzr);   // plane L
                hfh[kc] = *(const bf16x8*)((const char*)s_hh + b);
                hfl[kc] = *(const bf16x8*)((const char*)s_hl + b);
            }
        }
        bf16x8 xfh[2], xfl[2];
        #pragma unroll
        for (int kc = 0; kc < 2; ++kc) {
            int b = lm * 128 + ((kc * 64 + lq * 16) ^ swzr);
            xfh[kc] = *(const bf16x8*)((const char*)s_xh + b);
            xfl[kc] = *(const bf16x8*)((const char*)s_xl + b);
        }

        f32x4 a0 = {0.f,0.f,0.f,0.f}, a1 = a0, a2 = a0, a3 = a0;

        if (u > 0) { HPASS }           // h(s0-1)W -> acc rows 0-7 only

        #pragma unroll                  // x-pass: register weights
        for (int kc = 0; kc < 2; ++kc) {
            MM4(xfh[kc], wir[kc][0][0], wir[kc][1][0], wir[kc][2][0], wir[kc][3][0])
            MM4(xfl[kc], wir[kc][0][0], wir[kc][1][0], wir[kc][2][0], wir[kc][3][0])
            MM4(xfh[kc], wir[kc][0][1], wir[kc][1][1], wir[kc][2][1], wir[kc][3][1])
        }

        {   // even pointwise: rows 0-7
            float gi0, gi1, gf0, gf1, gg0, gg1, go0, go1;
            REDIST_E(a0, gi0, gi1)
            REDIST_E(a1, gf0, gf1)
            REDIST_E(a2, gg0, gg1)
            REDIST_E(a3, go0, go1)
            PWBODY(gi0, gf0, gg0, go0, gi1, gf1, gg1, go1, wb0e, wb1e)
        }

        // ================= ODD step s1 = 2u+1 =================
        __syncthreads();   // h(s0) (plane H) visible
        #pragma unroll
        for (int kc = 0; kc < 4; ++kc) {
            int b = 4096 + lm * 256 + ((kc * 64 + lq * 16) ^ swzr);  // plane H
            hfh[kc] = *(const bf16x8*)((const char*)s_hh + b);
            hfl[kc] = *(const bf16x8*)((const char*)s_hl + b);
        }
        HPASS                          // h(s0)W -> acc rows 8-15 only

        {   // odd pointwise: rows 8-15
            float gi0, gi1, gf0, gf1, gg0, gg1, go0, go1;
            REDIST_O(a0, gi0, gi1)
            REDIST_O(a1, gf0, gf1)
            REDIST_O(a2, gg0, gg1)
            REDIST_O(a3, go0, go1)
            PWBODY(gi0, gf0, gg0, go0, gi1, gf1, gg1, go1, wb0o, wb1o)
        }
        xv = xvn;
    }
    __syncthreads();

    // ---- epilogue: h(SEQ-1)=h(49) is odd -> plane L rows 0-7 ----
    {
        const int row = t >> 5;
        if (row < 8) {
            const int j0 = t & 31, j1 = (t & 31) + 32;
            const int rswz = (row & 7) << 4;
            float accA = b_out[j0], accB = b_out[j1];
            #pragma unroll
            for (int kq = 0; kq < 16; ++kq) {
                int b = row * 256 + ((kq * 16) ^ rswz);
                bf16x8 hh8 = *(const bf16x8*)((const char*)s_hh + b);
                bf16x8 hl8 = *(const bf16x8*)((const char*)s_hl + b);
                #pragma unroll
                for (int e = 0; e < 8; ++e) {
                    float h = bf2f((unsigned short)hh8[e]) + bf2f((unsigned short)hl8[e]);
                    int k = kq * 8 + e;
                    accA = fmaf(h, W_out[j0 * 128 + k], accA);
                    accB = fmaf(h, W_out[j1 * 128 + k], accB);
                }
            }
            out[(row0 + row) * 64 + j0] = accA;
            out[(row0 + row) * 64 + j1] = accB;
        }
    }
}

// ---------------------------------------------------------------------------
extern "C" void kernel_launch(void* const* d_in, const int* in_sizes, int n_in,
                              void* d_out, int out_size, void* d_ws, size_t ws_size,
                              hipStream_t stream) {
    (void)in_sizes; (void)n_in; (void)out_size; (void)ws_size;
    const float* seqs  = (const float*)d_in[0];
    const float* ets   = (const float*)d_in[1];
    const int*   masks = (const int*)d_in[2];
    const float* Wf  = (const float*)d_in[3];
    const float* bf  = (const float*)d_in[4];
    const float* Wk  = (const float*)d_in[5];
    const float* bk  = (const float*)d_in[6];
    const float* Wq  = (const float*)d_in[7];
    const float* bq  = (const float*)d_in[8];
    const float* Wv  = (const float*)d_in[9];
    const float* bv  = (const float*)d_in[10];
    const float* Wih = (const float*)d_in[11];
    const float* Whh = (const float*)d_in[12];
    const float* bih = (const float*)d_in[13];
    const float* bhh = (const float*)d_in[14];
    const float* Wo  = (const float*)d_in[15];
    const float* bo  = (const float*)d_in[16];

    // ws layout: whF 256K | wiF 128K | ctx 26.2M  (attn tables in device globals)
    char* ws = (char*)d_ws;
    bf16x8* whF = (bf16x8*)(ws);
    bf16x8* wiF = (bf16x8*)(ws + 262144);
    float*  ctx = (float*) (ws + 262144 + 131072);

    hipLaunchKernelGGL(prep_all, dim3(52), dim3(512), 0, stream,
                       Wih, Whh, whF, wiF, Wf, bf, Wq, bq, Wv, Wk, bk);
    hipLaunchKernelGGL(edge_attn_ctx, dim3(4096), dim3(64), 0, stream,
                       seqs, ets, masks, bv, ctx);
    hipLaunchKernelGGL(lstm_mfma, dim3(256), dim3(512), 0, stream,
                       ctx, whF, wiF, bih, bhh, Wo, bo, (float*)d_out);
}